// Round 4
// baseline (1416.416 us; speedup 1.0000x reference)
//
#include <hip/hip_runtime.h>

#define NSP 32
#define BB  16
#define CC  64
#define HW  (512 * 512)

#define BLOCK  256
#define CHUNK  8192
#define NCHUNK (HW / CHUNK)        // 32
#define KIT    (CHUNK / 4 / BLOCK) // 8 float4-iters per thread per pass
#define STR    (NSP + 1)           // 33 floats: ODD word stride -> bank = (lane+bin)%32, conflict-free

// Barrier that drains LDS (lgkmcnt) but NOT vmcnt: all cross-thread deps are
// LDS-only, so prefetched global loads stay in flight across fold phases.
#define BAR() asm volatile("s_waitcnt lgkmcnt(0)\n\ts_barrier" ::: "memory")

// ---------------------------------------------------------------------------
// Segmented sums + counts. Per-thread privatized LDS bins; accumulation is
// fire-and-forget ds_add_f32 (no exposed RMW latency, no aliasing waits).
// Each block: one 8192-pixel chunk, all 64 channels in pairs, depth-2
// register prefetch (preA/preB) so HBM never idles.
// ---------------------------------------------------------------------------
__global__ __launch_bounds__(BLOCK) void sp_accum(const float* __restrict__ feats,
                                                  const int*   __restrict__ spidx,
                                                  float*       __restrict__ sums  /*[B][C][NSP]*/,
                                                  float*       __restrict__ counts/*[B][NSP]*/)
{
    __shared__ float  s_pA[BLOCK][STR];   // 33.8 KB — even channel plane
    __shared__ float  s_pB[BLOCK][STR];   // 33.8 KB — odd channel plane
    __shared__ float2 s_pe[8][NSP];       // 2 KB — partials, even passes
    __shared__ float2 s_po[8][NSP];       // 2 KB — partials, odd passes

    const int tid  = threadIdx.x;
    const int b    = blockIdx.y;
    const int pix0 = blockIdx.x * CHUNK;
    const int bin  = tid & 31;
    const int grp  = tid >> 5;

    float* rowA = s_pA[tid];
    float* rowB = s_pB[tid];

    // --- own pixel indices -> registers (no cross-thread reuse -> no LDS) ---
    uchar4 uu[KIT];
    {
        const int4* ip = (const int4*)(spidx + (size_t)b * HW + pix0);
#pragma unroll
        for (int k = 0; k < KIT; ++k) {
            int4 v = ip[k * BLOCK + tid];
            uu[k] = make_uchar4((unsigned char)(v.x & 31), (unsigned char)(v.y & 31),
                                (unsigned char)(v.z & 31), (unsigned char)(v.w & 31));
        }
    }
#pragma unroll
    for (int s = 0; s < NSP; ++s) { rowA[s] = 0.f; rowB[s] = 0.f; }

    // --- depth-2 prefetch prologue: pass0 -> preA, pass1 -> preB ---
    const float* fb = feats + (size_t)b * CC * HW + pix0;
    float4 preA[KIT][2], preB[KIT][2];
#pragma unroll
    for (int k = 0; k < KIT; ++k) {
        preA[k][0] = ((const float4*)(fb))[k * BLOCK + tid];
        preA[k][1] = ((const float4*)(fb + (size_t)HW))[k * BLOCK + tid];
    }
#pragma unroll
    for (int k = 0; k < KIT; ++k) {
        preB[k][0] = ((const float4*)(fb + (size_t)2 * HW))[k * BLOCK + tid];
        preB[k][1] = ((const float4*)(fb + (size_t)3 * HW))[k * BLOCK + tid];
    }

    // --- fused pixel counts (covers prefetch latency) ---
#pragma unroll
    for (int k = 0; k < KIT; ++k) {
        atomicAdd(&rowA[uu[k].x], 1.f);
        atomicAdd(&rowA[uu[k].y], 1.f);
        atomicAdd(&rowA[uu[k].z], 1.f);
        atomicAdd(&rowA[uu[k].w], 1.f);
    }
    BAR();
    {
        float a = 0.f;
#pragma unroll
        for (int m = 0; m < BLOCK / 8; ++m) a += s_pA[grp + m * 8][bin];
        s_pe[grp][bin].x = a;
    }
    BAR();
    if (tid < NSP) {
        float r = 0.f;
#pragma unroll
        for (int g = 0; g < 8; ++g) r += s_pe[g][tid].x;
        atomicAdd(&counts[b * NSP + tid], r);   // fire-and-forget
    }
#pragma unroll
    for (int s = 0; s < NSP; ++s) rowA[s] = 0.f;
    // no barrier needed: own-row rezero/adds are same-thread; pass0's BAR orders the rest

    // --- main channel-pair passes (2 barriers each) ---
    auto pass = [&](float4 (&pre)[KIT][2], int ch0, bool refill, float2 (*spart)[NSP]) {
        // accumulate from prefetched registers: fire-and-forget LDS atomics
#pragma unroll
        for (int k = 0; k < KIT; ++k) {
            float4 a = pre[k][0], c = pre[k][1];
            atomicAdd(&rowA[uu[k].x], a.x); atomicAdd(&rowB[uu[k].x], c.x);
            atomicAdd(&rowA[uu[k].y], a.y); atomicAdd(&rowB[uu[k].y], c.y);
            atomicAdd(&rowA[uu[k].z], a.z); atomicAdd(&rowB[uu[k].z], c.z);
            atomicAdd(&rowA[uu[k].w], a.w); atomicAdd(&rowB[uu[k].w], c.w);
        }
        // refill this buffer for pass p+2 (consumed ~a full pass later)
        if (refill) {
            const float* g0 = fb + (size_t)(ch0 + 4) * HW;
#pragma unroll
            for (int k = 0; k < KIT; ++k) {
                pre[k][0] = ((const float4*)g0)[k * BLOCK + tid];
                pre[k][1] = ((const float4*)(g0 + (size_t)HW))[k * BLOCK + tid];
            }
        }
        BAR();   // drain ds_adds
        {
            float fa = 0.f, fbs = 0.f;
#pragma unroll
            for (int m = 0; m < BLOCK / 8; ++m) {
                fa  += s_pA[grp + m * 8][bin];
                fbs += s_pB[grp + m * 8][bin];
            }
            spart[grp][bin] = make_float2(fa, fbs);
        }
        BAR();   // spart complete; all reads of private rows complete
        // rezero own rows (same-thread ordering vs next pass's adds)
#pragma unroll
        for (int s = 0; s < NSP; ++s) { rowA[s] = 0.f; rowB[s] = 0.f; }
        if (tid < NSP) {
            float2 r = spart[0][tid];
#pragma unroll
            for (int g = 1; g < 8; ++g) { r.x += spart[g][tid].x; r.y += spart[g][tid].y; }
            atomicAdd(&sums[((size_t)b * CC + ch0)     * NSP + tid], r.x);  // fire-and-forget
            atomicAdd(&sums[((size_t)b * CC + ch0 + 1) * NSP + tid], r.y);
        }
        // no trailing barrier: spart is parity-double-buffered; next pass's BAR
        // orders flush-reads (this pass) before the next same-parity fold-write.
    };

    for (int cp = 0; cp < CC / 2; cp += 2) {
        pass(preA, 2 * cp,     cp + 2 < CC / 2, s_pe);
        pass(preB, 2 * cp + 2, cp + 3 < CC / 2, s_po);
    }
}

// ---------------------------------------------------------------------------
// Mean + pairwise similarity. One block per batch.
// out layout: sp [B][NSP][C] at 0, sim [B][NSP][NSP] at B*NSP*C
// ---------------------------------------------------------------------------
__global__ __launch_bounds__(BLOCK) void sp_finalize(const float* __restrict__ sums,
                                                     const float* __restrict__ counts,
                                                     float*       __restrict__ out)
{
    __shared__ float s_sp[NSP][CC + 1];
    const int b   = blockIdx.x;
    const int tid = threadIdx.x;

    for (int i = tid; i < NSP * CC; i += BLOCK) {
        int sp = i >> 6, c = i & 63;
        float cnt = counts[b * NSP + sp];
        float s   = sums[((size_t)b * CC + c) * NSP + sp];
        float v   = (cnt > 0.0f) ? (s / cnt) : 0.0f;
        s_sp[sp][c] = v;
        out[(size_t)b * NSP * CC + (size_t)sp * CC + c] = v;
    }
    __syncthreads();

    for (int p = tid; p < NSP * NSP; p += BLOCK) {
        int i = p >> 5, j = p & 31;
        float acc = 0.0f;
#pragma unroll
        for (int c = 0; c < CC; ++c) {
            float d = s_sp[i][c] - s_sp[j][c];
            acc = fmaf(d, d, acc);
        }
        out[(size_t)BB * NSP * CC + (size_t)b * NSP * NSP + p] = 1.0f - 0.5f * acc;
    }
}

// ---------------------------------------------------------------------------
extern "C" void kernel_launch(void* const* d_in, const int* in_sizes, int n_in,
                              void* d_out, int out_size, void* d_ws, size_t ws_size,
                              hipStream_t stream)
{
    const float* feats = (const float*)d_in[0];
    const int*   spidx = (const int*)d_in[1];
    float*       out   = (float*)d_out;

    float* sums   = (float*)d_ws;                     // B*C*NSP = 32768 floats
    float* counts = sums + (size_t)BB * CC * NSP;     // B*NSP   = 512 floats

    hipMemsetAsync(d_ws, 0, ((size_t)BB * CC * NSP + (size_t)BB * NSP) * sizeof(float), stream);

    dim3 g1(NCHUNK, BB);
    sp_accum<<<g1, BLOCK, 0, stream>>>(feats, spidx, sums, counts);

    sp_finalize<<<BB, BLOCK, 0, stream>>>(sums, counts, out);
}

// Round 5
// 214.433 us; speedup vs baseline: 6.6054x; 6.6054x over previous
//
#include <hip/hip_runtime.h>

#define NSP 32
#define BB  16
#define CC  64
#define HW  (512 * 512)

#define BLOCK  256
#define CHUNK  8192
#define NCHUNK (HW / CHUNK)        // 32
#define KIT    (CHUNK / 4 / BLOCK) // 8 float4-iters per thread per pass
#define STR    (NSP + 1)           // 33: odd stride -> conflict-free banks; slot 32 = dummy sink

// Barrier that drains LDS (lgkmcnt) but NOT vmcnt: all cross-thread deps are
// LDS-only, so prefetched global loads stay in flight across fold phases.
#define BAR() asm volatile("s_waitcnt lgkmcnt(0)\n\ts_barrier" ::: "memory")

// ---------------------------------------------------------------------------
// Segmented sums + counts. Per-thread privatized float2 LDS bins, plain RMW
// (NOT ds atomics — those measured 7x slower). Accum reads are quad-batched
// (4 independent ds_read_b64, one wait) with in-register duplicate-merge;
// duplicate writes are redirected to the pad slot (bin 32).
// ---------------------------------------------------------------------------
__global__ __launch_bounds__(BLOCK) void sp_accum(const float* __restrict__ feats,
                                                  const int*   __restrict__ spidx,
                                                  float*       __restrict__ sums  /*[B][C][NSP]*/,
                                                  float*       __restrict__ counts/*[B][NSP]*/)
{
    __shared__ float2 s_priv[BLOCK][STR];   // 67.6 KB private bins
    __shared__ float2 s_pe[8][NSP];         // partials, even passes
    __shared__ float2 s_po[8][NSP];         // partials, odd passes

    const int tid  = threadIdx.x;
    const int b    = blockIdx.y;
    const int pix0 = blockIdx.x * CHUNK;
    const int bin  = tid & 31;
    const int grp  = tid >> 5;

    float2* row = s_priv[tid];

    // --- own pixel indices -> registers ---
    uchar4 uu[KIT];
    {
        const int4* ip = (const int4*)(spidx + (size_t)b * HW + pix0);
#pragma unroll
        for (int k = 0; k < KIT; ++k) {
            int4 v = ip[k * BLOCK + tid];
            uu[k] = make_uchar4((unsigned char)(v.x & 31), (unsigned char)(v.y & 31),
                                (unsigned char)(v.z & 31), (unsigned char)(v.w & 31));
        }
    }
#pragma unroll
    for (int s = 0; s < STR; ++s) row[s] = make_float2(0.f, 0.f);

    // --- depth-1 prefetch prologue: pass 0 (channels 0,1) ---
    const float* fb = feats + (size_t)b * CC * HW + pix0;
    float4 pre[KIT][2];
#pragma unroll
    for (int k = 0; k < KIT; ++k) {
        pre[k][0] = ((const float4*)fb)[k * BLOCK + tid];
        pre[k][1] = ((const float4*)(fb + (size_t)HW))[k * BLOCK + tid];
    }

    // --- fused pixel counts (plain RMW on .x plane; runs under prefetch) ---
#pragma unroll
    for (int k = 0; k < KIT; ++k) {
        row[uu[k].x].x += 1.f;
        row[uu[k].y].x += 1.f;
        row[uu[k].z].x += 1.f;
        row[uu[k].w].x += 1.f;
    }
    BAR();
    {
        float a = 0.f;
#pragma unroll
        for (int m = 0; m < BLOCK / 8; ++m) a += s_priv[grp + m * 8][bin].x;
        s_pe[grp][bin].x = a;
    }
    BAR();
#pragma unroll
    for (int s = 0; s < STR; ++s) row[s] = make_float2(0.f, 0.f);
    if (tid < NSP) {
        float r = 0.f;
#pragma unroll
        for (int g = 0; g < 8; ++g) r += s_pe[g][tid].x;
        atomicAdd(&counts[b * NSP + tid], r);
    }
    // no barrier needed: next fold is after pass 0's BAR; s_pe rewrite also after it

    // --- main channel-pair passes, 2 barriers each ---
    for (int p = 0; p < CC / 2; ++p) {
        const int ch0 = 2 * p;
        float2 (*part)[NSP] = (p & 1) ? s_po : s_pe;

        // accumulate: quad-batched reads + duplicate-merge
#pragma unroll
        for (int k = 0; k < KIT; ++k) {
            const uchar4 u = uu[k];
            const float4 a = pre[k][0], c = pre[k][1];
            // 4 independent reads (batched -> single lgkm wait)
            float2 t0 = row[u.x], t1 = row[u.y], t2 = row[u.z], t3 = row[u.w];
            float2 cx = make_float2(a.x, c.x);
            float2 cy = make_float2(a.y, c.y);
            float2 cz = make_float2(a.z, c.z);
            float2 cw = make_float2(a.w, c.w);
            const bool ky  = (u.y == u.x);
            const bool kz1 = (u.z == u.x), kz2 = (u.z == u.y);
            const bool kw1 = (u.w == u.x), kw2 = (u.w == u.y), kw3 = (u.w == u.z);
            if (ky)  { cx.x += cy.x; cx.y += cy.y; }
            if (kz1) { cx.x += cz.x; cx.y += cz.y; }
            else if (kz2) { cy.x += cz.x; cy.y += cz.y; }
            if (kw1) { cx.x += cw.x; cx.y += cw.y; }
            else if (kw2) { cy.x += cw.x; cy.y += cw.y; }
            else if (kw3) { cz.x += cw.x; cz.y += cw.y; }
            // dead writes -> pad slot 32 (never folded)
            const unsigned wy = ky ? 32u : (unsigned)u.y;
            const unsigned wz = (kz1 | kz2) ? 32u : (unsigned)u.z;
            const unsigned ww = (kw1 | kw2 | kw3) ? 32u : (unsigned)u.w;
            row[u.x] = make_float2(t0.x + cx.x, t0.y + cx.y);
            row[wy]  = make_float2(t1.x + cy.x, t1.y + cy.y);
            row[wz]  = make_float2(t2.x + cz.x, t2.y + cz.y);
            row[ww]  = make_float2(t3.x + cw.x, t3.y + cw.y);
        }
        // refill for pass p+1 — loads stay in flight across both barriers
        if (p + 1 < CC / 2) {
            const float* g0 = fb + (size_t)(ch0 + 2) * HW;
#pragma unroll
            for (int k = 0; k < KIT; ++k) {
                pre[k][0] = ((const float4*)g0)[k * BLOCK + tid];
                pre[k][1] = ((const float4*)(g0 + (size_t)HW))[k * BLOCK + tid];
            }
        }
        BAR();
        // fold 256 private copies: 8 threads per bin, 32 copies each
        {
            float2 acc = make_float2(0.f, 0.f);
#pragma unroll
            for (int m = 0; m < BLOCK / 8; ++m) {
                float2 v = s_priv[grp + m * 8][bin];
                acc.x += v.x; acc.y += v.y;
            }
            part[grp][bin] = acc;
        }
        BAR();
        // rezero own row (ordered vs next pass's fold by next BAR)
#pragma unroll
        for (int s = 0; s < STR; ++s) row[s] = make_float2(0.f, 0.f);
        if (tid < NSP) {
            float2 r = part[0][tid];
#pragma unroll
            for (int g = 1; g < 8; ++g) { r.x += part[g][tid].x; r.y += part[g][tid].y; }
            atomicAdd(&sums[((size_t)b * CC + ch0)     * NSP + tid], r.x);
            atomicAdd(&sums[((size_t)b * CC + ch0 + 1) * NSP + tid], r.y);
        }
        // no trailing barrier: partials are parity-double-buffered
    }
}

// ---------------------------------------------------------------------------
// Mean + pairwise similarity. One block per batch.
// out layout: sp [B][NSP][C] at 0, sim [B][NSP][NSP] at B*NSP*C
// ---------------------------------------------------------------------------
__global__ __launch_bounds__(BLOCK) void sp_finalize(const float* __restrict__ sums,
                                                     const float* __restrict__ counts,
                                                     float*       __restrict__ out)
{
    __shared__ float s_sp[NSP][CC + 1];
    const int b   = blockIdx.x;
    const int tid = threadIdx.x;

    for (int i = tid; i < NSP * CC; i += BLOCK) {
        int sp = i >> 6, c = i & 63;
        float cnt = counts[b * NSP + sp];
        float s   = sums[((size_t)b * CC + c) * NSP + sp];
        float v   = (cnt > 0.0f) ? (s / cnt) : 0.0f;
        s_sp[sp][c] = v;
        out[(size_t)b * NSP * CC + (size_t)sp * CC + c] = v;
    }
    __syncthreads();

    for (int p = tid; p < NSP * NSP; p += BLOCK) {
        int i = p >> 5, j = p & 31;
        float acc = 0.0f;
#pragma unroll
        for (int c = 0; c < CC; ++c) {
            float d = s_sp[i][c] - s_sp[j][c];
            acc = fmaf(d, d, acc);
        }
        out[(size_t)BB * NSP * CC + (size_t)b * NSP * NSP + p] = 1.0f - 0.5f * acc;
    }
}

// ---------------------------------------------------------------------------
extern "C" void kernel_launch(void* const* d_in, const int* in_sizes, int n_in,
                              void* d_out, int out_size, void* d_ws, size_t ws_size,
                              hipStream_t stream)
{
    const float* feats = (const float*)d_in[0];
    const int*   spidx = (const int*)d_in[1];
    float*       out   = (float*)d_out;

    float* sums   = (float*)d_ws;                     // B*C*NSP = 32768 floats
    float* counts = sums + (size_t)BB * CC * NSP;     // B*NSP   = 512 floats

    hipMemsetAsync(d_ws, 0, ((size_t)BB * CC * NSP + (size_t)BB * NSP) * sizeof(float), stream);

    dim3 g1(NCHUNK, BB);
    sp_accum<<<g1, BLOCK, 0, stream>>>(feats, spidx, sums, counts);

    sp_finalize<<<BB, BLOCK, 0, stream>>>(sums, counts, out);
}